// Round 1
// baseline (21659.328 us; speedup 1.0000x reference)
//
#include <hip/hip_runtime.h>
#include <hip/hip_bf16.h>
#include <stdint.h>

#define SEQ   1024
#define NB    4
#define BT    4096   // NB*SEQ rows
#define DM    512
#define DI    1024

typedef float  f32x4  __attribute__((ext_vector_type(4)));
typedef short  bf16x8 __attribute__((ext_vector_type(8)));

__device__ __forceinline__ float bf2f(unsigned short u){
  union { unsigned int i; float f; } v; v.i = ((unsigned int)u) << 16; return v.f;
}
__device__ __forceinline__ unsigned short f2bf(float f){
  union { float f; unsigned int i; } v; v.f = f;
  unsigned int x = v.i;
  return (unsigned short)((x + 0x7fffu + ((x >> 16) & 1u)) >> 16);
}
__device__ __forceinline__ float sigmoidf_(float x){ return 1.f/(1.f + __expf(-x)); }
__device__ __forceinline__ float siluf_(float x){ return x/(1.f + __expf(-x)); }

// ---------------- fp32 -> bf16 weight conversion ----------------
__global__ __launch_bounds__(256) void cvt_kernel(const float* __restrict__ in,
                                                  unsigned short* __restrict__ out, int n){
  int i = blockIdx.x*256 + threadIdx.x;
  int stride = gridDim.x*256;
  for (; i < n; i += stride) out[i] = f2bf(in[i]);
}

// ---------------- fused residual-add + layernorm ----------------
// res = hidden (+ resid_in);  y = LN(res)*gamma+beta -> bf16 and/or f32
__global__ __launch_bounds__(256) void ln_kernel(
    const float* __restrict__ hidden, const float* __restrict__ resid_in,
    const float* __restrict__ gamma,  const float* __restrict__ beta,
    float* __restrict__ resid_out, unsigned short* __restrict__ out_bf,
    float* __restrict__ out_f32)
{
  int wave = threadIdx.x >> 6;
  int lane = threadIdx.x & 63;
  int row  = blockIdx.x*4 + wave;               // 4096 rows
  size_t base = (size_t)row * DM + lane*8;
  float4 a0 = *(const float4*)(hidden + base);
  float4 a1 = *(const float4*)(hidden + base + 4);
  if (resid_in){
    float4 b0 = *(const float4*)(resid_in + base);
    float4 b1 = *(const float4*)(resid_in + base + 4);
    a0.x+=b0.x; a0.y+=b0.y; a0.z+=b0.z; a0.w+=b0.w;
    a1.x+=b1.x; a1.y+=b1.y; a1.z+=b1.z; a1.w+=b1.w;
  }
  if (resid_out){
    *(float4*)(resid_out + base)     = a0;
    *(float4*)(resid_out + base + 4) = a1;
  }
  float xv[8] = {a0.x,a0.y,a0.z,a0.w,a1.x,a1.y,a1.z,a1.w};
  float s = 0.f, sq = 0.f;
  #pragma unroll
  for (int q=0;q<8;q++){ s += xv[q]; sq += xv[q]*xv[q]; }
  #pragma unroll
  for (int off=32; off; off>>=1){ s += __shfl_xor(s, off); sq += __shfl_xor(sq, off); }
  float mean = s * (1.f/DM);
  float var  = sq * (1.f/DM) - mean*mean;
  float rstd = rsqrtf(var + 1e-5f);
  float4 g0 = *(const float4*)(gamma + lane*8);
  float4 g1 = *(const float4*)(gamma + lane*8 + 4);
  float4 e0 = *(const float4*)(beta  + lane*8);
  float4 e1 = *(const float4*)(beta  + lane*8 + 4);
  float gv[8] = {g0.x,g0.y,g0.z,g0.w,g1.x,g1.y,g1.z,g1.w};
  float ev[8] = {e0.x,e0.y,e0.z,e0.w,e1.x,e1.y,e1.z,e1.w};
  float yv[8];
  #pragma unroll
  for (int q=0;q<8;q++) yv[q] = (xv[q]-mean)*rstd*gv[q] + ev[q];
  if (out_bf){
    uint4 p;
    p.x = (unsigned)f2bf(yv[0]) | ((unsigned)f2bf(yv[1])<<16);
    p.y = (unsigned)f2bf(yv[2]) | ((unsigned)f2bf(yv[3])<<16);
    p.z = (unsigned)f2bf(yv[4]) | ((unsigned)f2bf(yv[5])<<16);
    p.w = (unsigned)f2bf(yv[6]) | ((unsigned)f2bf(yv[7])<<16);
    *(uint4*)(out_bf + base) = p;
  }
  if (out_f32){
    float4 o0 = {yv[0],yv[1],yv[2],yv[3]};
    float4 o1 = {yv[4],yv[5],yv[6],yv[7]};
    *(float4*)(out_f32 + base)     = o0;
    *(float4*)(out_f32 + base + 4) = o1;
  }
}

// ---------------- bf16 MFMA GEMM:  C[M,N] = A[M,K] * B[N,K]^T + bias ----------------
// block = 256 thr = 4 waves (2x2), wave tile 64x64, block tile 128x128
__global__ __launch_bounds__(256) void gemm_kernel(
    const unsigned short* __restrict__ A, const unsigned short* __restrict__ B,
    const float* __restrict__ bias,
    float* __restrict__ Cf, unsigned short* __restrict__ Cbf,
    int M, int N, int K)
{
  int tid  = threadIdx.x;
  int wid  = tid >> 6, lane = tid & 63;
  int wm   = wid >> 1, wn = wid & 1;
  int tm   = blockIdx.y*128 + wm*64;
  int tn   = blockIdx.x*128 + wn*64;
  int l15  = lane & 15;
  int lk   = (lane >> 4) * 8;

  f32x4 acc[4][4] = {};
  for (int kk = 0; kk < K; kk += 32){
    bf16x8 a[4], b[4];
    #pragma unroll
    for (int f=0; f<4; ++f)
      a[f] = *(const bf16x8*)(A + (size_t)(tm + f*16 + l15)*K + kk + lk);
    #pragma unroll
    for (int f=0; f<4; ++f)
      b[f] = *(const bf16x8*)(B + (size_t)(tn + f*16 + l15)*K + kk + lk);
    #pragma unroll
    for (int i=0;i<4;i++)
      #pragma unroll
      for (int j=0;j<4;j++)
        acc[i][j] = __builtin_amdgcn_mfma_f32_16x16x32_bf16(a[i], b[j], acc[i][j], 0,0,0);
  }
  int crow0 = (lane>>4)*4;
  #pragma unroll
  for (int i=0;i<4;i++){
    #pragma unroll
    for (int j=0;j<4;j++){
      int col = tn + j*16 + l15;
      float bv = bias ? bias[col] : 0.f;
      #pragma unroll
      for (int r=0;r<4;r++){
        int row = tm + i*16 + crow0 + r;
        float val = acc[i][j][r] + bv;
        if (Cf)  Cf [(size_t)row*N + col] = val;
        else     Cbf[(size_t)row*N + col] = f2bf(val);
      }
    }
  }
}

// ---------------- causal depthwise conv(4) + SiLU ----------------
__global__ __launch_bounds__(256) void conv_silu_kernel(
  const float* __restrict__ xz, const float* __restrict__ cw, const float* __restrict__ cb,
  unsigned short* __restrict__ xconv)
{
  int idx = blockIdx.x*256 + threadIdx.x;       // < 4*1024*1024
  int c = idx & (DI-1);
  int t = (idx >> 10) & (SEQ-1);
  const float* base = xz + (size_t)(idx >> 10) * (2*DI) + c;   // row (b*SEQ+t), col c
  float w0 = cw[c*4+0], w1 = cw[c*4+1], w2 = cw[c*4+2], w3 = cw[c*4+3];
  float acc = cb[c] + base[0] * w3;
  if (t >= 1) acc += base[-(2*DI)]   * w2;
  if (t >= 2) acc += base[-(4*DI)]   * w1;
  if (t >= 3) acc += base[-(6*DI)]   * w0;
  xconv[idx] = f2bf(siluf_(acc));
}

// ---------------- persistent GRU scan ----------------
// 256 wgs: b = wg>>6 (batch), g = wg&63 -> outputs i in [g*16, g*16+16)
// thread: il = tid>>4 (output), ks = tid&15 (64-wide K slice), whh slice in VGPRs.
__global__ __launch_bounds__(256, 1) void scan_kernel(
    const unsigned short* __restrict__ xih,   // [BT,3*DI] bf16 (bih included)
    const float* __restrict__ xz,             // [BT,2*DI] (z at +DI)
    const unsigned short* __restrict__ whh,   // [3*DI,DI] bf16
    const float* __restrict__ bhh,            // [3*DI]
    float* __restrict__ hbuf,                 // [2][NB][DI]
    unsigned short* __restrict__ xout,        // [BT,DI] bf16
    unsigned int* __restrict__ ctr,           // [NB*64] (use ctr[b*64])
    int layer)
{
  const int wg  = blockIdx.x;
  const int b   = wg >> 6;
  const int g   = wg & 63;
  const int tid = threadIdx.x;
  const int il  = tid >> 4;
  const int ks  = tid & 15;
  const int i   = g*16 + il;
  const int k0  = ks*64;

  uint32_t wr[32], wz[32], wn[32];
  {
    const uint32_t* pr = (const uint32_t*)(whh + (size_t)i*DI + k0);
    const uint32_t* pz = (const uint32_t*)(whh + (size_t)(DI+i)*DI + k0);
    const uint32_t* pn = (const uint32_t*)(whh + (size_t)(2*DI+i)*DI + k0);
    #pragma unroll
    for (int j=0;j<32;j++) wr[j]=pr[j];
    #pragma unroll
    for (int j=0;j<32;j++) wz[j]=pz[j];
    #pragma unroll
    for (int j=0;j<32;j++) wn[j]=pn[j];
  }
  const float bhr = bhh[i], bhz = bhh[DI+i], bhn = bhh[2*DI+i];

  __shared__ float hsh[16*66];   // 64-float slices, stride 66 (bank-conflict-free)

  unsigned int* myctr = ctr + b*64;
  const unsigned int cbase = (unsigned int)layer << 16;   // layer*65536

  for (int t=0; t<SEQ; ++t){
    const size_t rowx = (size_t)(b*SEQ + t);
    // x-side loads (independent of h; hide under staging+dot)
    float xr  = bf2f(xih[rowx*3*DI + i]);
    float xzg = bf2f(xih[rowx*3*DI + DI + i]);
    float xn  = bf2f(xih[rowx*3*DI + 2*DI + i]);
    float zg  = xz[rowx*2*DI + DI + i];

    if (t == 0){
      for (int j=tid; j<16*66; j+=256) hsh[j] = 0.f;
    } else {
      float* hs = hbuf + (size_t)(((t&1)*NB + b))*DI + tid*4;
      float h0 = __hip_atomic_load(hs+0, __ATOMIC_RELAXED, __HIP_MEMORY_SCOPE_AGENT);
      float h1 = __hip_atomic_load(hs+1, __ATOMIC_RELAXED, __HIP_MEMORY_SCOPE_AGENT);
      float h2 = __hip_atomic_load(hs+2, __ATOMIC_RELAXED, __HIP_MEMORY_SCOPE_AGENT);
      float h3 = __hip_atomic_load(hs+3, __ATOMIC_RELAXED, __HIP_MEMORY_SCOPE_AGENT);
      int k = tid*4;
      int sidx = (k & 63) + (k >> 6)*66;
      hsh[sidx+0]=h0; hsh[sidx+1]=h1; hsh[sidx+2]=h2; hsh[sidx+3]=h3;
    }
    __syncthreads();

    float ar=0.f, az=0.f, an=0.f;
    const float* hrow = hsh + ks*66;
    #pragma unroll
    for (int j=0;j<32;j++){
      float2 h2v = *(const float2*)(hrow + 2*j);
      union {uint32_t u; float f;} cv;
      float rlo,rhi,zlo,zhi,nlo,nhi;
      cv.u = wr[j] << 16;          rlo = cv.f;
      cv.u = wr[j] & 0xffff0000u;  rhi = cv.f;
      cv.u = wz[j] << 16;          zlo = cv.f;
      cv.u = wz[j] & 0xffff0000u;  zhi = cv.f;
      cv.u = wn[j] << 16;          nlo = cv.f;
      cv.u = wn[j] & 0xffff0000u;  nhi = cv.f;
      ar = fmaf(rlo, h2v.x, ar); ar = fmaf(rhi, h2v.y, ar);
      az = fmaf(zlo, h2v.x, az); az = fmaf(zhi, h2v.y, az);
      an = fmaf(nlo, h2v.x, an); an = fmaf(nhi, h2v.y, an);
    }
    #pragma unroll
    for (int off=1; off<16; off<<=1){
      ar += __shfl_xor(ar, off);
      az += __shfl_xor(az, off);
      an += __shfl_xor(an, off);
    }

    if (ks == 0){
      float r = sigmoidf_(xr + ar + bhr);
      float z = sigmoidf_(xzg + az + bhz);
      float n = tanhf(xn + r*(an + bhn));
      float hprev = hsh[(i & 63) + (i >> 6)*66];
      float hnew  = (1.f - z)*n + z*hprev;
      __hip_atomic_store(hbuf + (size_t)((((t+1)&1)*NB + b))*DI + i, hnew,
                         __ATOMIC_RELAXED, __HIP_MEMORY_SCOPE_AGENT);
      xout[rowx*DI + i] = f2bf(hnew * siluf_(zg));
    }
    __syncthreads();   // drains vmcnt: h stores at LLC before the arrive below
    if (tid == 0){
      __hip_atomic_fetch_add(myctr, 1u, __ATOMIC_RELAXED, __HIP_MEMORY_SCOPE_AGENT);
      if (t < SEQ-1){
        const unsigned int tgt = cbase + 64u*(unsigned)(t+1);
        while (__hip_atomic_load(myctr, __ATOMIC_RELAXED, __HIP_MEMORY_SCOPE_AGENT) < tgt) {}
      }
    }
    if (t < SEQ-1) __syncthreads();
  }
}

// ---------------- host ----------------
extern "C" void kernel_launch(void* const* d_in, const int* in_sizes, int n_in,
                              void* d_out, int out_size, void* d_ws, size_t ws_size,
                              hipStream_t stream)
{
  (void)in_sizes; (void)n_in; (void)out_size; (void)ws_size;
  const float* x      = (const float*)d_in[0];
  const float* norm_w = (const float*)d_in[1];
  const float* norm_b = (const float*)d_in[2];
  const float* inw    = (const float*)d_in[3];
  const float* inb    = (const float*)d_in[4];
  const float* convw  = (const float*)d_in[5];
  const float* convb  = (const float*)d_in[6];
  const float* wih    = (const float*)d_in[7];
  const float* whh    = (const float*)d_in[8];
  const float* bih    = (const float*)d_in[9];
  const float* bhh    = (const float*)d_in[10];
  const float* outw   = (const float*)d_in[11];
  const float* outb   = (const float*)d_in[12];
  const float* normfw = (const float*)d_in[13];
  const float* normfb = (const float*)d_in[14];
  float* out = (float*)d_out;

  char* ws = (char*)d_ws;
  size_t off = 0;
  auto alloc = [&](size_t bytes)->void*{ void* p = ws + off; off = (off + bytes + 255) & ~(size_t)255; return p; };
  float*          resid  = (float*)         alloc((size_t)BT*DM*4);
  unsigned short* lnbf   = (unsigned short*)alloc((size_t)BT*DM*2);
  float*          xz     = (float*)         alloc((size_t)BT*2*DI*4);
  unsigned short* xconv  = (unsigned short*)alloc((size_t)BT*DI*2);
  unsigned short* xihb   = (unsigned short*)alloc((size_t)BT*3*DI*2);
  unsigned short* xoutb  = (unsigned short*)alloc((size_t)BT*DI*2);
  float*          hidden = (float*)         alloc((size_t)BT*DM*4);
  unsigned short* w1bf   = (unsigned short*)alloc((size_t)2048*512*2);
  unsigned short* wihbf  = (unsigned short*)alloc((size_t)3072*1024*2);
  unsigned short* whhbf  = (unsigned short*)alloc((size_t)3072*1024*2);
  unsigned short* woutbf = (unsigned short*)alloc((size_t)512*1024*2);
  float*          hbuf   = (float*)         alloc((size_t)2*NB*DI*4);
  unsigned int*   ctr    = (unsigned int*)  alloc(1024);

  hipMemsetAsync(ctr, 0, 1024, stream);

  const float* hid_in = x;
  const float* res_in = nullptr;
  for (int l = 0; l < 6; ++l){
    ln_kernel<<<1024, 256, 0, stream>>>(hid_in, res_in, norm_w + l*DM, norm_b + l*DM,
                                        resid, lnbf, nullptr);
    cvt_kernel<<<2048, 256, 0, stream>>>(inw  + (size_t)l*2048*512,  w1bf,   2048*512);
    cvt_kernel<<<2048, 256, 0, stream>>>(wih  + (size_t)l*3072*1024, wihbf,  3072*1024);
    cvt_kernel<<<2048, 256, 0, stream>>>(whh  + (size_t)l*3072*1024, whhbf,  3072*1024);
    cvt_kernel<<<2048, 256, 0, stream>>>(outw + (size_t)l*512*1024,  woutbf, 512*1024);
    // in_proj: xz = ln * inw^T + inb   [4096 x 2048], fp32 out
    gemm_kernel<<<dim3(2048/128, BT/128), 256, 0, stream>>>(lnbf, w1bf, inb + l*2048,
                                                            xz, nullptr, BT, 2048, 512);
    conv_silu_kernel<<<(BT*DI)/256, 256, 0, stream>>>(xz, convw + (size_t)l*DI*4,
                                                      convb + (size_t)l*DI, xconv);
    // gru input: xih = xconv * wih^T + bih  [4096 x 3072], bf16 out
    gemm_kernel<<<dim3(3072/128, BT/128), 256, 0, stream>>>(xconv, wihbf, bih + l*3072,
                                                            nullptr, xihb, BT, 3072, 1024);
    scan_kernel<<<256, 256, 0, stream>>>(xihb, xz, whhbf, bhh + l*3072, hbuf, xoutb, ctr, l);
    // out proj: hidden = xout * outw^T + outb  [4096 x 512], fp32 out
    gemm_kernel<<<dim3(512/128, BT/128), 256, 0, stream>>>(xoutb, woutbf, outb + l*DM,
                                                           hidden, nullptr, BT, 512, 1024);
    hid_in = hidden; res_in = resid;
  }
  ln_kernel<<<1024, 256, 0, stream>>>(hidden, resid, normfw, normfb,
                                      nullptr, nullptr, out);
}

// Round 2
// 17957.993 us; speedup vs baseline: 1.2061x; 1.2061x over previous
//
#include <hip/hip_runtime.h>
#include <hip/hip_bf16.h>
#include <stdint.h>

#define SEQ   1024
#define NB    4
#define BT    4096   // NB*SEQ rows
#define DM    512
#define DI    1024

typedef float  f32x4  __attribute__((ext_vector_type(4)));
typedef short  bf16x8 __attribute__((ext_vector_type(8)));

__device__ __forceinline__ float bf2f(unsigned short u){
  union { unsigned int i; float f; } v; v.i = ((unsigned int)u) << 16; return v.f;
}
__device__ __forceinline__ unsigned short f2bf(float f){
  union { float f; unsigned int i; } v; v.f = f;
  unsigned int x = v.i;
  return (unsigned short)((x + 0x7fffu + ((x >> 16) & 1u)) >> 16);
}
__device__ __forceinline__ float bits2f(uint32_t u){
  union { uint32_t i; float f; } v; v.i = u; return v.f;
}
__device__ __forceinline__ float sigmoidf_(float x){ return __fdividef(1.f, 1.f + __expf(-x)); }
__device__ __forceinline__ float siluf_(float x){ return x * __fdividef(1.f, 1.f + __expf(-x)); }
__device__ __forceinline__ float tanhf_(float x){
  float e = __expf(2.f*x);
  return 1.f - __fdividef(2.f, e + 1.f);
}

// ---------------- fp32 -> bf16 weight conversion ----------------
__global__ __launch_bounds__(256) void cvt_kernel(const float* __restrict__ in,
                                                  unsigned short* __restrict__ out, int n){
  int i = blockIdx.x*256 + threadIdx.x;
  int stride = gridDim.x*256;
  for (; i < n; i += stride) out[i] = f2bf(in[i]);
}

// ---------------- fused residual-add + layernorm ----------------
__global__ __launch_bounds__(256) void ln_kernel(
    const float* __restrict__ hidden, const float* __restrict__ resid_in,
    const float* __restrict__ gamma,  const float* __restrict__ beta,
    float* __restrict__ resid_out, unsigned short* __restrict__ out_bf,
    float* __restrict__ out_f32)
{
  int wave = threadIdx.x >> 6;
  int lane = threadIdx.x & 63;
  int row  = blockIdx.x*4 + wave;               // 4096 rows
  size_t base = (size_t)row * DM + lane*8;
  float4 a0 = *(const float4*)(hidden + base);
  float4 a1 = *(const float4*)(hidden + base + 4);
  if (resid_in){
    float4 b0 = *(const float4*)(resid_in + base);
    float4 b1 = *(const float4*)(resid_in + base + 4);
    a0.x+=b0.x; a0.y+=b0.y; a0.z+=b0.z; a0.w+=b0.w;
    a1.x+=b1.x; a1.y+=b1.y; a1.z+=b1.z; a1.w+=b1.w;
  }
  if (resid_out){
    *(float4*)(resid_out + base)     = a0;
    *(float4*)(resid_out + base + 4) = a1;
  }
  float xv[8] = {a0.x,a0.y,a0.z,a0.w,a1.x,a1.y,a1.z,a1.w};
  float s = 0.f, sq = 0.f;
  #pragma unroll
  for (int q=0;q<8;q++){ s += xv[q]; sq += xv[q]*xv[q]; }
  #pragma unroll
  for (int off=32; off; off>>=1){ s += __shfl_xor(s, off); sq += __shfl_xor(sq, off); }
  float mean = s * (1.f/DM);
  float var  = sq * (1.f/DM) - mean*mean;
  float rstd = rsqrtf(var + 1e-5f);
  float4 g0 = *(const float4*)(gamma + lane*8);
  float4 g1 = *(const float4*)(gamma + lane*8 + 4);
  float4 e0 = *(const float4*)(beta  + lane*8);
  float4 e1 = *(const float4*)(beta  + lane*8 + 4);
  float gv[8] = {g0.x,g0.y,g0.z,g0.w,g1.x,g1.y,g1.z,g1.w};
  float ev[8] = {e0.x,e0.y,e0.z,e0.w,e1.x,e1.y,e1.z,e1.w};
  float yv[8];
  #pragma unroll
  for (int q=0;q<8;q++) yv[q] = (xv[q]-mean)*rstd*gv[q] + ev[q];
  if (out_bf){
    uint4 p;
    p.x = (unsigned)f2bf(yv[0]) | ((unsigned)f2bf(yv[1])<<16);
    p.y = (unsigned)f2bf(yv[2]) | ((unsigned)f2bf(yv[3])<<16);
    p.z = (unsigned)f2bf(yv[4]) | ((unsigned)f2bf(yv[5])<<16);
    p.w = (unsigned)f2bf(yv[6]) | ((unsigned)f2bf(yv[7])<<16);
    *(uint4*)(out_bf + base) = p;
  }
  if (out_f32){
    float4 o0 = {yv[0],yv[1],yv[2],yv[3]};
    float4 o1 = {yv[4],yv[5],yv[6],yv[7]};
    *(float4*)(out_f32 + base)     = o0;
    *(float4*)(out_f32 + base + 4) = o1;
  }
}

// ---------------- bf16 MFMA GEMM:  C[M,N] = A[M,K] * B[N,K]^T + bias ----------------
__global__ __launch_bounds__(256) void gemm_kernel(
    const unsigned short* __restrict__ A, const unsigned short* __restrict__ B,
    const float* __restrict__ bias,
    float* __restrict__ Cf, unsigned short* __restrict__ Cbf,
    int M, int N, int K)
{
  int tid  = threadIdx.x;
  int wid  = tid >> 6, lane = tid & 63;
  int wm   = wid >> 1, wn = wid & 1;
  int tm   = blockIdx.y*128 + wm*64;
  int tn   = blockIdx.x*128 + wn*64;
  int l15  = lane & 15;
  int lk   = (lane >> 4) * 8;

  f32x4 acc[4][4] = {};
  for (int kk = 0; kk < K; kk += 32){
    bf16x8 a[4], b[4];
    #pragma unroll
    for (int f=0; f<4; ++f)
      a[f] = *(const bf16x8*)(A + (size_t)(tm + f*16 + l15)*K + kk + lk);
    #pragma unroll
    for (int f=0; f<4; ++f)
      b[f] = *(const bf16x8*)(B + (size_t)(tn + f*16 + l15)*K + kk + lk);
    #pragma unroll
    for (int i=0;i<4;i++)
      #pragma unroll
      for (int j=0;j<4;j++)
        acc[i][j] = __builtin_amdgcn_mfma_f32_16x16x32_bf16(a[i], b[j], acc[i][j], 0,0,0);
  }
  int crow0 = (lane>>4)*4;
  #pragma unroll
  for (int i=0;i<4;i++){
    #pragma unroll
    for (int j=0;j<4;j++){
      int col = tn + j*16 + l15;
      float bv = bias ? bias[col] : 0.f;
      #pragma unroll
      for (int r=0;r<4;r++){
        int row = tm + i*16 + crow0 + r;
        float val = acc[i][j][r] + bv;
        if (Cf)  Cf [(size_t)row*N + col] = val;
        else     Cbf[(size_t)row*N + col] = f2bf(val);
      }
    }
  }
}

// ---------------- causal depthwise conv(4) + SiLU ----------------
__global__ __launch_bounds__(256) void conv_silu_kernel(
  const float* __restrict__ xz, const float* __restrict__ cw, const float* __restrict__ cb,
  unsigned short* __restrict__ xconv)
{
  int idx = blockIdx.x*256 + threadIdx.x;       // < 4*1024*1024
  int c = idx & (DI-1);
  int t = (idx >> 10) & (SEQ-1);
  const float* base = xz + (size_t)(idx >> 10) * (2*DI) + c;
  float w0 = cw[c*4+0], w1 = cw[c*4+1], w2 = cw[c*4+2], w3 = cw[c*4+3];
  float acc = cb[c] + base[0] * w3;
  if (t >= 1) acc += base[-(2*DI)]   * w2;
  if (t >= 2) acc += base[-(4*DI)]   * w1;
  if (t >= 3) acc += base[-(6*DI)]   * w0;
  xconv[idx] = f2bf(siluf_(acc));
}

// ---------------- persistent GRU scan (flag-sync version) ----------------
// 256 wgs: b = wg>>6 (batch), g = wg&63 -> outputs i in [g*16, g*16+16)
// thread: il = tid>>4 (output), ks = tid&15 (64-wide K slice).
// whh slice pre-unpacked to 192 fp32 VGPRs.
// Sync: per-wave flag (256 per batch) stored after s_waitcnt vmcnt(0);
// each thread polls one flag; __syncthreads is the AND. hsh parity
// double-buffer makes the end-of-step barrier unnecessary.
__global__ __launch_bounds__(256, 1) void scan_kernel(
    const unsigned short* __restrict__ xih,   // [BT,3*DI] bf16 (bih included)
    const float* __restrict__ xz,             // [BT,2*DI] (z at +DI)
    const unsigned short* __restrict__ whh,   // [3*DI,DI] bf16
    const float* __restrict__ bhh,            // [3*DI]
    float* __restrict__ hbuf,                 // [2][NB][DI]
    unsigned short* __restrict__ xout,        // [BT,DI] bf16
    unsigned int* __restrict__ flags,         // [NB*256]
    int layer)
{
  const int wg  = blockIdx.x;
  const int b   = wg >> 6;
  const int g   = wg & 63;
  const int tid = threadIdx.x;
  const int wv  = tid >> 6;
  const int il  = tid >> 4;
  const int ks  = tid & 15;
  const int i   = g*16 + il;
  const int k0  = ks*64;

  // ---- pre-unpack whh slice to fp32 (static indices only) ----
  float wr[64], wz[64], wn[64];
  {
    const uint32_t* pr = (const uint32_t*)(whh + (size_t)i*DI + k0);
    const uint32_t* pz = (const uint32_t*)(whh + (size_t)(DI+i)*DI + k0);
    const uint32_t* pn = (const uint32_t*)(whh + (size_t)(2*DI+i)*DI + k0);
    #pragma unroll
    for (int j=0;j<32;j++){
      uint32_t u = pr[j];
      wr[2*j]   = bits2f(u << 16);
      wr[2*j+1] = bits2f(u & 0xffff0000u);
    }
    #pragma unroll
    for (int j=0;j<32;j++){
      uint32_t u = pz[j];
      wz[2*j]   = bits2f(u << 16);
      wz[2*j+1] = bits2f(u & 0xffff0000u);
    }
    #pragma unroll
    for (int j=0;j<32;j++){
      uint32_t u = pn[j];
      wn[2*j]   = bits2f(u << 16);
      wn[2*j+1] = bits2f(u & 0xffff0000u);
    }
  }
  const float bhr = bhh[i], bhz = bhh[DI+i], bhn = bhh[2*DI+i];

  __shared__ float hsh[2][16*68];   // parity-double-buffered, stride 68

  const unsigned int tagbase = (unsigned int)layer * 1024u;

  // ---- x prefetch registers (producer lanes ks==0 only) ----
  float xr_c=0.f, xzg_c=0.f, xn_c=0.f, zg_c=0.f;
  float xr_n=0.f, xzg_n=0.f, xn_n=0.f, zg_n=0.f;
  if (ks == 0){
    const size_t r0 = (size_t)b*SEQ;
    xr_c  = bf2f(xih[r0*3*DI + i]);
    xzg_c = bf2f(xih[r0*3*DI + DI + i]);
    xn_c  = bf2f(xih[r0*3*DI + 2*DI + i]);
    zg_c  = xz[r0*2*DI + DI + i];
  }

  for (int t=0; t<SEQ; ++t){
    const int par = t & 1;
    if (t == 0){
      for (int j=tid; j<16*68; j+=256) hsh[0][j] = 0.f;
    } else {
      // wait for all 256 producer waves of this batch
      const unsigned int tgt = tagbase + (unsigned)t;
      while (__hip_atomic_load(flags + b*256 + tid, __ATOMIC_RELAXED,
                               __HIP_MEMORY_SCOPE_AGENT) < tgt) {}
      __syncthreads();   // A: whole wg has seen all flags
      // load h(t) -> LDS parity buffer
      const float* hsrc = hbuf + ((size_t)par*NB + b)*DI + tid*4;
      unsigned long long q0 = __hip_atomic_load((const unsigned long long*)hsrc,
                                                __ATOMIC_RELAXED, __HIP_MEMORY_SCOPE_AGENT);
      unsigned long long q1 = __hip_atomic_load((const unsigned long long*)hsrc + 1,
                                                __ATOMIC_RELAXED, __HIP_MEMORY_SCOPE_AGENT);
      int k = tid*4;
      float* dst = &hsh[par][(k & 63) + (k >> 6)*68];
      union { unsigned long long q; float f[2]; } c0, c1;
      c0.q = q0; c1.q = q1;
      dst[0]=c0.f[0]; dst[1]=c0.f[1]; dst[2]=c1.f[0]; dst[3]=c1.f[1];
    }
    __syncthreads();     // B: hsh[par] ready

    // ---- dot: 16 x (ds_read_b128 + 12 fma) ----
    float ar=0.f, az=0.f, an=0.f;
    const float* hrow = &hsh[par][ks*68];
    #pragma unroll
    for (int j=0;j<16;j++){
      f32x4 h4 = *(const f32x4*)(hrow + 4*j);
      ar = fmaf(wr[4*j+0], h4.x, ar); az = fmaf(wz[4*j+0], h4.x, az); an = fmaf(wn[4*j+0], h4.x, an);
      ar = fmaf(wr[4*j+1], h4.y, ar); az = fmaf(wz[4*j+1], h4.y, az); an = fmaf(wn[4*j+1], h4.y, an);
      ar = fmaf(wr[4*j+2], h4.z, ar); az = fmaf(wz[4*j+2], h4.z, az); an = fmaf(wn[4*j+2], h4.z, an);
      ar = fmaf(wr[4*j+3], h4.w, ar); az = fmaf(wz[4*j+3], h4.w, az); an = fmaf(wn[4*j+3], h4.w, an);
    }
    #pragma unroll
    for (int off=1; off<16; off<<=1){
      ar += __shfl_xor(ar, off);
      az += __shfl_xor(az, off);
      an += __shfl_xor(an, off);
    }

    if (ks == 0){
      float r = sigmoidf_(xr_c + ar + bhr);
      float z = sigmoidf_(xzg_c + az + bhz);
      float n = tanhf_(xn_c + r*(an + bhn));
      float hprev = hsh[par][(i & 63) + (i >> 6)*68];
      float hnew  = (1.f - z)*n + z*hprev;
      __hip_atomic_store(hbuf + ((size_t)((t+1)&1)*NB + b)*DI + i, hnew,
                         __ATOMIC_RELAXED, __HIP_MEMORY_SCOPE_AGENT);
      const size_t rowx = (size_t)(b*SEQ + t);
      xout[rowx*DI + i] = f2bf(hnew * siluf_(zg_c));
    }
    // drain this wave's h/xout stores to the coherence point, then arrive
    asm volatile("s_waitcnt vmcnt(0)" ::: "memory");
    if (t < SEQ-1){
      if ((tid & 63) == 0)
        __hip_atomic_store(flags + b*256 + g*4 + wv, tagbase + (unsigned)(t+1),
                           __ATOMIC_RELAXED, __HIP_MEMORY_SCOPE_AGENT);
      // prefetch x(t+1) — latency hides under next step's poll + h load
      if (ks == 0){
        const size_t r1 = (size_t)(b*SEQ + t + 1);
        xr_n  = bf2f(xih[r1*3*DI + i]);
        xzg_n = bf2f(xih[r1*3*DI + DI + i]);
        xn_n  = bf2f(xih[r1*3*DI + 2*DI + i]);
        zg_n  = xz[r1*2*DI + DI + i];
      }
      xr_c = xr_n; xzg_c = xzg_n; xn_c = xn_n; zg_c = zg_n;
    }
  }
}

// ---------------- host ----------------
extern "C" void kernel_launch(void* const* d_in, const int* in_sizes, int n_in,
                              void* d_out, int out_size, void* d_ws, size_t ws_size,
                              hipStream_t stream)
{
  (void)in_sizes; (void)n_in; (void)out_size; (void)ws_size;
  const float* x      = (const float*)d_in[0];
  const float* norm_w = (const float*)d_in[1];
  const float* norm_b = (const float*)d_in[2];
  const float* inw    = (const float*)d_in[3];
  const float* inb    = (const float*)d_in[4];
  const float* convw  = (const float*)d_in[5];
  const float* convb  = (const float*)d_in[6];
  const float* wih    = (const float*)d_in[7];
  const float* whh    = (const float*)d_in[8];
  const float* bih    = (const float*)d_in[9];
  const float* bhh    = (const float*)d_in[10];
  const float* outw   = (const float*)d_in[11];
  const float* outb   = (const float*)d_in[12];
  const float* normfw = (const float*)d_in[13];
  const float* normfb = (const float*)d_in[14];
  float* out = (float*)d_out;

  char* ws = (char*)d_ws;
  size_t off = 0;
  auto alloc = [&](size_t bytes)->void*{ void* p = ws + off; off = (off + bytes + 255) & ~(size_t)255; return p; };
  float*          resid  = (float*)         alloc((size_t)BT*DM*4);
  unsigned short* lnbf   = (unsigned short*)alloc((size_t)BT*DM*2);
  float*          xz     = (float*)         alloc((size_t)BT*2*DI*4);
  unsigned short* xconv  = (unsigned short*)alloc((size_t)BT*DI*2);
  unsigned short* xihb   = (unsigned short*)alloc((size_t)BT*3*DI*2);
  unsigned short* xoutb  = (unsigned short*)alloc((size_t)BT*DI*2);
  float*          hidden = (float*)         alloc((size_t)BT*DM*4);
  unsigned short* w1bf   = (unsigned short*)alloc((size_t)2048*512*2);
  unsigned short* wihbf  = (unsigned short*)alloc((size_t)3072*1024*2);
  unsigned short* whhbf  = (unsigned short*)alloc((size_t)3072*1024*2);
  unsigned short* woutbf = (unsigned short*)alloc((size_t)512*1024*2);
  float*          hbuf   = (float*)         alloc((size_t)2*NB*DI*4);
  unsigned int*   flags  = (unsigned int*)  alloc(NB*256*4);

  hipMemsetAsync(flags, 0, NB*256*4, stream);

  const float* hid_in = x;
  const float* res_in = nullptr;
  for (int l = 0; l < 6; ++l){
    ln_kernel<<<1024, 256, 0, stream>>>(hid_in, res_in, norm_w + l*DM, norm_b + l*DM,
                                        resid, lnbf, nullptr);
    cvt_kernel<<<2048, 256, 0, stream>>>(inw  + (size_t)l*2048*512,  w1bf,   2048*512);
    cvt_kernel<<<2048, 256, 0, stream>>>(wih  + (size_t)l*3072*1024, wihbf,  3072*1024);
    cvt_kernel<<<2048, 256, 0, stream>>>(whh  + (size_t)l*3072*1024, whhbf,  3072*1024);
    cvt_kernel<<<2048, 256, 0, stream>>>(outw + (size_t)l*512*1024,  woutbf, 512*1024);
    // in_proj: xz = ln * inw^T + inb   [4096 x 2048], fp32 out
    gemm_kernel<<<dim3(2048/128, BT/128), 256, 0, stream>>>(lnbf, w1bf, inb + l*2048,
                                                            xz, nullptr, BT, 2048, 512);
    conv_silu_kernel<<<(BT*DI)/256, 256, 0, stream>>>(xz, convw + (size_t)l*DI*4,
                                                      convb + (size_t)l*DI, xconv);
    // gru input: xih = xconv * wih^T + bih  [4096 x 3072], bf16 out
    gemm_kernel<<<dim3(3072/128, BT/128), 256, 0, stream>>>(xconv, wihbf, bih + l*3072,
                                                            nullptr, xihb, BT, 3072, 1024);
    scan_kernel<<<256, 256, 0, stream>>>(xihb, xz, whhbf, bhh + l*3072, hbuf, xoutb, flags, l);
    // out proj: hidden = xout * outw^T + outb  [4096 x 512], fp32 out
    gemm_kernel<<<dim3(512/128, BT/128), 256, 0, stream>>>(xoutb, woutbf, outb + l*DM,
                                                           hidden, nullptr, BT, 512, 1024);
    hid_in = hidden; res_in = resid;
  }
  ln_kernel<<<1024, 256, 0, stream>>>(hidden, resid, normfw, normfb,
                                      nullptr, nullptr, out);
}